// Round 9
// baseline (117.839 us; speedup 1.0000x reference)
//
#include <hip/hip_runtime.h>
#include <math.h>

#define BB 32
#define SS 4096
#define HH 512
#define CHUNKS 32
#define ROWS_PER_BLOCK 128          // rows per k_flash block
#define ROWS_PER_WAVE 32
#define TROWS 2                     // rows per DMA tile (4 KB)
#define NTILES (ROWS_PER_WAVE / TROWS)   // 16

// ws layout (float offsets):
#define WS_TPART    0               // [8][64][512]  target partials   (262144)
#define WS_SCORES   262144          // [2][B][S]                        (262144)
#define WS_PML      524288          // [2][B][CHUNKS][2]                (4096)
#define WS_PACC     528384          // [2][B][CHUNKS][H]                (1048576)
#define WS_GPART    1609728         // [16][2][32][256]                 (262144)

__device__ static inline void gload_lds16(const float* g, float* l) {
    __builtin_amdgcn_global_load_lds(
        (const __attribute__((address_space(1))) void*)g,
        (__attribute__((address_space(3))) void*)l, 16, 0, 0);
}
__device__ static inline void gload_lds16_nt(const float* g, float* l) {
    __builtin_amdgcn_global_load_lds(
        (const __attribute__((address_space(1))) void*)g,
        (__attribute__((address_space(3))) void*)l, 16, 0, 2 /* NT */);
}

// --------------------------------------------- K1: target partial GEMV
// grid (8 rc, 64 bb); light: runs in ~2-3 us before flash
__global__ __launch_bounds__(256) void k_target(
    const float* __restrict__ tree_in, const float* __restrict__ text_in,
    const float* __restrict__ W_in, float* __restrict__ ws)
{
    const int rc = blockIdx.x;
    const int bb = blockIdx.y;          // br*32 + b
    const int br = bb >> 5, b = bb & 31;
    const float* inp = (br == 0 ? tree_in : text_in) + b * HH;

    __shared__ float sx[64];
    if (threadIdx.x < 64) sx[threadIdx.x] = inp[rc * 64 + threadIdx.x];
    __syncthreads();

    const int c = threadIdx.x;
    const float* wp = W_in + (size_t)(rc * 64) * HH + c;
    float a0 = 0.f, a1 = 0.f;
    #pragma unroll 8
    for (int j = 0; j < 64; ++j) {
        const float x = sx[j];
        a0 += x * wp[(size_t)j * HH];
        a1 += x * wp[(size_t)j * HH + 256];
    }
    float* tp = ws + WS_TPART + (size_t)(rc * 64 + bb) * HH;
    tp[c] = a0;
    tp[c + 256] = a1;
}

// ------------------------------------------------- K2: flash pass over context
// grid (2, CHUNKS+8, BB):
//   y <  CHUNKS : flash block (br=x, chunk=y, b=z)  — inner loop UNCHANGED
//   y >= CHUNKS : input-half W_out GEMV block (flash-independent work hidden
//                 inside this dispatch; rcp=y-CHUNKS, half=x, b=z)
__global__ __launch_bounds__(256) void k_flash(
    const float* __restrict__ tree_ctx, const float* __restrict__ text_ctx,
    const float* __restrict__ tree_mask, const float* __restrict__ text_mask,
    const float* __restrict__ tree_in, const float* __restrict__ text_in,
    const float* __restrict__ W_out, float* __restrict__ ws)
{
    const int br = blockIdx.x;
    const int y = blockIdx.y;
    const int b = blockIdx.z;

    __shared__ float smem[4 * 2 * 1024 + 128 + 128 + 8 + 8];  // 33.9 KB

    if (y >= CHUNKS) {
        // ---- input-half W_out GEMV: seg1 (tree_in) rcp<4, seg3 (text_in) rcp>=4
        const int tid = threadIdx.x;
        const int rcp = y - CHUNKS;         // 0..7
        const int half = br;
        const int seg = (rcp < 4) ? 1 : 3;
        const int slice = rcp & 3;
        const int gi = seg * 4 + slice;     // 4..7, 12..15
        const float* src = (seg == 1 ? tree_in : text_in) + (size_t)b * HH;

        float* const sx = smem;
        if (tid < 128) sx[tid] = src[slice * 128 + tid];
        __syncthreads();

        const float* wp = W_out + (size_t)(seg * 512 + slice * 128) * HH
                        + half * 256 + tid;
        float a = 0.f;
        #pragma unroll 8
        for (int j = 0; j < 128; ++j)
            a += sx[j] * wp[(size_t)j * HH];

        ws[WS_GPART + (size_t)((gi * 2 + half) * BB + b) * 256 + tid] = a;
        return;
    }

    const int chunk = y;
    const int bi = br * BB + b;

    const float* ctx = (br == 0 ? tree_ctx : text_ctx) + (size_t)b * SS * HH;
    const float* mask = (br == 0 ? tree_mask : text_mask) + (size_t)b * SS;
    float* scores_g = ws + WS_SCORES + (size_t)bi * SS;

    const int wave = threadIdx.x >> 6;
    const int lane = threadIdx.x & 63;
    const int lane4 = lane * 4;

    float* const tiles_w = smem + wave * 2048;                 // [2][1024]
    float* const smask = smem + 8192;
    float* const ssc = smem + 8320;
    float* const lm = smem + 8448;
    float* const ll = smem + 8456;

    float* const buf0 = tiles_w;
    float* const buf1 = tiles_w + 1024;
    const int s0 = chunk * ROWS_PER_BLOCK + wave * ROWS_PER_WAVE;
    const int r0 = wave * ROWS_PER_WAVE;

    #define ISSUE_TILE(TT, BP) do {                                          \
        const float* _g = ctx + (size_t)(s0 + (TT) * TROWS) * HH + lane4;    \
        if (br == 0) {                                                       \
            _Pragma("unroll")                                                \
            for (int j = 0; j < 4; ++j)                                      \
                gload_lds16(_g + j * 256, (BP) + j * 256);                   \
        } else {                                                             \
            _Pragma("unroll")                                                \
            for (int j = 0; j < 4; ++j)                                      \
                gload_lds16_nt(_g + j * 256, (BP) + j * 256);                \
        }                                                                    \
    } while (0)

    ISSUE_TILE(0, buf0);
    __builtin_amdgcn_sched_barrier(0);

    if (threadIdx.x < ROWS_PER_BLOCK)
        smask[threadIdx.x] = mask[chunk * ROWS_PER_BLOCK + threadIdx.x];

    float4 t0 = make_float4(0.f, 0.f, 0.f, 0.f);
    float4 t1 = make_float4(0.f, 0.f, 0.f, 0.f);
    #pragma unroll
    for (int rc = 0; rc < 8; ++rc) {
        const float* tp = ws + WS_TPART + (size_t)(rc * 64 + bi) * HH;
        const float4 u = *(const float4*)(tp + lane4);
        const float4 v = *(const float4*)(tp + 256 + lane4);
        t0.x += u.x; t0.y += u.y; t0.z += u.z; t0.w += u.w;
        t1.x += v.x; t1.y += v.y; t1.z += v.z; t1.w += v.w;
    }
    __syncthreads();

    float m = -INFINITY, l = 0.f;
    float4 acc_a = make_float4(0.f, 0.f, 0.f, 0.f);
    float4 acc_b = make_float4(0.f, 0.f, 0.f, 0.f);

    for (int tt = 0; tt < NTILES; ++tt) {
        if (tt + 1 < NTILES) {
            float* nb = ((tt + 1) & 1) ? buf1 : buf0;
            ISSUE_TILE(tt + 1, nb);
            asm volatile("s_waitcnt vmcnt(4)" ::: "memory");
        } else {
            asm volatile("s_waitcnt vmcnt(0)" ::: "memory");
        }
        __builtin_amdgcn_sched_barrier(0);

        const float* bp = (tt & 1) ? buf1 : buf0;
        const int rbase = r0 + tt * TROWS;

        const float4 c00 = *(const float4*)(bp + lane4);
        const float4 c01 = *(const float4*)(bp + 256 + lane4);
        const float4 c10 = *(const float4*)(bp + 512 + lane4);
        const float4 c11 = *(const float4*)(bp + 768 + lane4);

        float d0 = c00.x*t0.x + c00.y*t0.y + c00.z*t0.z + c00.w*t0.w
                 + c01.x*t1.x + c01.y*t1.y + c01.z*t1.z + c01.w*t1.w;
        float d1 = c10.x*t0.x + c10.y*t0.y + c10.z*t0.z + c10.w*t0.w
                 + c11.x*t1.x + c11.y*t1.y + c11.z*t1.z + c11.w*t1.w;
        #pragma unroll
        for (int off = 1; off < 64; off <<= 1) {
            d0 += __shfl_xor(d0, off);
            d1 += __shfl_xor(d1, off);
        }

        const float sc0 = d0 * smask[rbase + 0];
        const float sc1 = d1 * smask[rbase + 1];
        if (lane == 0) ssc[rbase + 0] = sc0;
        if (lane == 1) ssc[rbase + 1] = sc1;

        const float mx = fmaxf(sc0, sc1);
        if (mx > m + 8.f) {                 // deferred-max rescale
            const float e = __expf(m - mx); // m==-inf -> 0
            l *= e;
            acc_a.x *= e; acc_a.y *= e; acc_a.z *= e; acc_a.w *= e;
            acc_b.x *= e; acc_b.y *= e; acc_b.z *= e; acc_b.w *= e;
            m = mx;
        }
        const float p0 = __expf(sc0 - m);
        const float p1 = __expf(sc1 - m);
        l += p0 + p1;

        acc_a.x += p0*c00.x + p1*c10.x;
        acc_a.y += p0*c00.y + p1*c10.y;
        acc_a.z += p0*c00.z + p1*c10.z;
        acc_a.w += p0*c00.w + p1*c10.w;
        acc_b.x += p0*c01.x + p1*c11.x;
        acc_b.y += p0*c01.y + p1*c11.y;
        acc_b.z += p0*c01.z + p1*c11.z;
        acc_b.w += p0*c01.w + p1*c11.w;
    }
    #undef ISSUE_TILE

    __syncthreads();                         // all waves done with tiles
    float* const lacc_w = tiles_w;           // overlay: 512 floats per wave
    if (lane == 0) { lm[wave] = m; ll[wave] = l; }
    *(float4*)(lacc_w + lane4) = acc_a;
    *(float4*)(lacc_w + 256 + lane4) = acc_b;
    __syncthreads();

    const float M = fmaxf(fmaxf(lm[0], lm[1]), fmaxf(lm[2], lm[3]));
    const float e0 = __expf(lm[0] - M);
    const float e1 = __expf(lm[1] - M);
    const float e2 = __expf(lm[2] - M);
    const float e3 = __expf(lm[3] - M);

    float* pml = ws + WS_PML + (size_t)(bi * CHUNKS + chunk) * 2;
    float* pacc = ws + WS_PACC + (size_t)(bi * CHUNKS + chunk) * HH;
    for (int h = threadIdx.x; h < HH; h += 256)
        pacc[h] = smem[0 * 2048 + h] * e0 + smem[1 * 2048 + h] * e1
                + smem[2 * 2048 + h] * e2 + smem[3 * 2048 + h] * e3;
    if (threadIdx.x == 0) {
        pml[0] = M;
        pml[1] = ll[0] * e0 + ll[1] * e1 + ll[2] * e2 + ll[3] * e3;
    }
    if (threadIdx.x < ROWS_PER_BLOCK)
        scores_g[chunk * ROWS_PER_BLOCK + threadIdx.x] = ssc[threadIdx.x];
}

// -------- K3: weighted-half W_out GEMV (esc inline) + att ; grid (8,2,32)
__global__ __launch_bounds__(256) void k_wgemv(
    const float* __restrict__ W_out, const float* __restrict__ ws_ro,
    float* __restrict__ ws, float* __restrict__ out)
{
    const int rcp = blockIdx.x;     // 0..7: rc<4 -> tree_w slices, else text_w
    const int half = blockIdx.y;
    const int b = blockIdx.z;
    const int tid = threadIdx.x;

    const int br = (rcp < 4) ? 0 : 1;
    const int wseg = br * 2;              // comb segment 0 or 2
    const int slice = rcp & 3;
    const int gi = wseg * 4 + slice;      // 0..3, 8..11
    const int bi = br * BB + b;

    // softmax merge constants from pml
    const float* pml = ws_ro + WS_PML + (size_t)bi * CHUNKS * 2;
    __shared__ float esc[CHUNKS];
    __shared__ float sw[128];
    float M = -INFINITY;
    for (int c = 0; c < CHUNKS; ++c) M = fmaxf(M, pml[2 * c]);
    float L = 0.f;
    for (int c = 0; c < CHUNKS; ++c) L += pml[2 * c + 1] * __expf(pml[2 * c] - M);
    const float invL = 1.f / L;
    if (tid < CHUNKS) esc[tid] = __expf(pml[2 * tid] - M) * invL;
    __syncthreads();

    // weighted slice (128 h) from pacc
    const float* pacc = ws_ro + WS_PACC + (size_t)bi * CHUNKS * HH;
    if (tid < 128) {
        const int h = slice * 128 + tid;
        float a = 0.f;
        for (int c = 0; c < CHUNKS; ++c) a += pacc[(size_t)c * HH + h] * esc[c];
        sw[tid] = a;
    }

    // att slice: 512 elements at (slice*2+half)*512
    {
        const float* sc_g = ws_ro + WS_SCORES + (size_t)bi * SS;
        float* att = out + BB * HH + (size_t)bi * SS;
        const int s2 = (slice * 2 + half) * 512 + tid * 2;
        const float2 sc = *(const float2*)(sc_g + s2);
        float2 r;
        r.x = __expf(sc.x - M) * invL;
        r.y = __expf(sc.y - M) * invL;
        *(float2*)(att + s2) = r;
    }
    __syncthreads();

    // GEMV over the 128-row slice
    const float* wp = W_out + (size_t)(wseg * 512 + slice * 128) * HH
                    + half * 256 + tid;
    float a = 0.f;
    #pragma unroll 8
    for (int j = 0; j < 128; ++j)
        a += sw[j] * wp[(size_t)j * HH];

    ws[WS_GPART + (size_t)((gi * 2 + half) * BB + b) * 256 + tid] = a;
}

// -------------------- K4: reduce partials + tanh ; grid (2,32)
__global__ __launch_bounds__(256) void k_fin(
    const float* __restrict__ ws, float* __restrict__ out)
{
    const int half = blockIdx.x;
    const int b = blockIdx.y;
    const int tid = threadIdx.x;
    float v = 0.f;
    #pragma unroll
    for (int gi = 0; gi < 16; ++gi)
        v += ws[WS_GPART + (size_t)((gi * 2 + half) * BB + b) * 256 + tid];
    out[(size_t)b * HH + half * 256 + tid] = tanhf(v);
}

// ---------------------------------------------------------------------- launch
extern "C" void kernel_launch(void* const* d_in, const int* in_sizes, int n_in,
                              void* d_out, int out_size, void* d_ws, size_t ws_size,
                              hipStream_t stream)
{
    const float* tree_inputs  = (const float*)d_in[0];
    const float* tree_context = (const float*)d_in[1];
    const float* text_inputs  = (const float*)d_in[2];
    const float* text_context = (const float*)d_in[3];
    const float* tree_mask    = (const float*)d_in[4];
    const float* text_mask    = (const float*)d_in[5];
    const float* W_in         = (const float*)d_in[6];
    const float* W_out        = (const float*)d_in[7];
    float* out = (float*)d_out;
    float* ws = (float*)d_ws;

    k_target<<<dim3(8, 64), 256, 0, stream>>>(tree_inputs, text_inputs, W_in, ws);
    k_flash<<<dim3(2, CHUNKS + 8, BB), 256, 0, stream>>>(
        tree_context, text_context, tree_mask, text_mask,
        tree_inputs, text_inputs, W_out, ws);
    k_wgemv<<<dim3(8, 2, BB), 256, 0, stream>>>(W_out, ws, ws, out);
    k_fin<<<dim3(2, BB), 256, 0, stream>>>(ws, out);
}

// Round 10
// 110.195 us; speedup vs baseline: 1.0694x; 1.0694x over previous
//
#include <hip/hip_runtime.h>
#include <math.h>

#define BB 32
#define SS 4096
#define HH 512
#define CHUNKS 32
#define ROWS_PER_BLOCK 128          // rows per k_flash block
#define ROWS_PER_WAVE 32
#define TROWS 2                     // rows per DMA tile (4 KB)
#define NTILES (ROWS_PER_WAVE / TROWS)   // 16

// ws layout (float offsets):
#define WS_TPART    0               // [8][64][512]  target partials   (262144)
#define WS_SCORES   262144          // [2][B][S]                        (262144)
#define WS_PML      524288          // [2][B][CHUNKS][2]                (4096)
#define WS_PACC     528384          // [2][B][CHUNKS][H]                (1048576)
#define WS_GPART    1609728         // [16][2][32][256]                 (262144)

__device__ static inline void gload_lds16(const float* g, float* l) {
    __builtin_amdgcn_global_load_lds(
        (const __attribute__((address_space(1))) void*)g,
        (__attribute__((address_space(3))) void*)l, 16, 0, 0);
}
__device__ static inline void gload_lds16_nt(const float* g, float* l) {
    __builtin_amdgcn_global_load_lds(
        (const __attribute__((address_space(1))) void*)g,
        (__attribute__((address_space(3))) void*)l, 16, 0, 2 /* NT */);
}

// --------------------------------------------- K1: target partial GEMV
// grid (8 rc, 64 bb); light: ~2-3 us before flash
__global__ __launch_bounds__(256) void k_target(
    const float* __restrict__ tree_in, const float* __restrict__ text_in,
    const float* __restrict__ W_in, float* __restrict__ ws)
{
    const int rc = blockIdx.x;
    const int bb = blockIdx.y;          // br*32 + b
    const int br = bb >> 5, b = bb & 31;
    const float* inp = (br == 0 ? tree_in : text_in) + b * HH;

    __shared__ float sx[64];
    if (threadIdx.x < 64) sx[threadIdx.x] = inp[rc * 64 + threadIdx.x];
    __syncthreads();

    const int c = threadIdx.x;
    const float* wp = W_in + (size_t)(rc * 64) * HH + c;
    float a0 = 0.f, a1 = 0.f;
    #pragma unroll 8
    for (int j = 0; j < 64; ++j) {
        const float x = sx[j];
        a0 += x * wp[(size_t)j * HH];
        a1 += x * wp[(size_t)j * HH + 256];
    }
    float* tp = ws + WS_TPART + (size_t)(rc * 64 + bb) * HH;
    tp[c] = a0;
    tp[c + 256] = a1;
}

// ------------------------------------------------- K2: flash pass over context
// (byte-identical to round 7 — pinned at the delivered-read ceiling)
__global__ __launch_bounds__(256) void k_flash(
    const float* __restrict__ tree_ctx, const float* __restrict__ text_ctx,
    const float* __restrict__ tree_mask, const float* __restrict__ text_mask,
    float* __restrict__ ws)
{
    const int br = blockIdx.x;          // fastest: mixes L3-tree and NT-text blocks
    const int chunk = blockIdx.y;
    const int b = blockIdx.z;
    const int bi = br * BB + b;

    const float* ctx = (br == 0 ? tree_ctx : text_ctx) + (size_t)b * SS * HH;
    const float* mask = (br == 0 ? tree_mask : text_mask) + (size_t)b * SS;
    float* scores_g = ws + WS_SCORES + (size_t)bi * SS;

    const int wave = threadIdx.x >> 6;
    const int lane = threadIdx.x & 63;
    const int lane4 = lane * 4;

    __shared__ float smem[4 * 2 * 1024 + 128 + 128 + 8 + 8];  // 33.9 KB
    float* const tiles_w = smem + wave * 2048;                 // [2][1024]
    float* const smask = smem + 8192;
    float* const ssc = smem + 8320;
    float* const lm = smem + 8448;
    float* const ll = smem + 8456;

    float* const buf0 = tiles_w;
    float* const buf1 = tiles_w + 1024;
    const int s0 = chunk * ROWS_PER_BLOCK + wave * ROWS_PER_WAVE;
    const int r0 = wave * ROWS_PER_WAVE;

    #define ISSUE_TILE(TT, BP) do {                                          \
        const float* _g = ctx + (size_t)(s0 + (TT) * TROWS) * HH + lane4;    \
        if (br == 0) {                                                       \
            _Pragma("unroll")                                                \
            for (int j = 0; j < 4; ++j)                                      \
                gload_lds16(_g + j * 256, (BP) + j * 256);                   \
        } else {                                                             \
            _Pragma("unroll")                                                \
            for (int j = 0; j < 4; ++j)                                      \
                gload_lds16_nt(_g + j * 256, (BP) + j * 256);                \
        }                                                                    \
    } while (0)

    ISSUE_TILE(0, buf0);
    __builtin_amdgcn_sched_barrier(0);

    if (threadIdx.x < ROWS_PER_BLOCK)
        smask[threadIdx.x] = mask[chunk * ROWS_PER_BLOCK + threadIdx.x];

    float4 t0 = make_float4(0.f, 0.f, 0.f, 0.f);
    float4 t1 = make_float4(0.f, 0.f, 0.f, 0.f);
    #pragma unroll
    for (int rc = 0; rc < 8; ++rc) {
        const float* tp = ws + WS_TPART + (size_t)(rc * 64 + bi) * HH;
        const float4 u = *(const float4*)(tp + lane4);
        const float4 v = *(const float4*)(tp + 256 + lane4);
        t0.x += u.x; t0.y += u.y; t0.z += u.z; t0.w += u.w;
        t1.x += v.x; t1.y += v.y; t1.z += v.z; t1.w += v.w;
    }
    __syncthreads();

    float m = -INFINITY, l = 0.f;
    float4 acc_a = make_float4(0.f, 0.f, 0.f, 0.f);
    float4 acc_b = make_float4(0.f, 0.f, 0.f, 0.f);

    for (int tt = 0; tt < NTILES; ++tt) {
        if (tt + 1 < NTILES) {
            float* nb = ((tt + 1) & 1) ? buf1 : buf0;
            ISSUE_TILE(tt + 1, nb);
            asm volatile("s_waitcnt vmcnt(4)" ::: "memory");
        } else {
            asm volatile("s_waitcnt vmcnt(0)" ::: "memory");
        }
        __builtin_amdgcn_sched_barrier(0);

        const float* bp = (tt & 1) ? buf1 : buf0;
        const int rbase = r0 + tt * TROWS;

        const float4 c00 = *(const float4*)(bp + lane4);
        const float4 c01 = *(const float4*)(bp + 256 + lane4);
        const float4 c10 = *(const float4*)(bp + 512 + lane4);
        const float4 c11 = *(const float4*)(bp + 768 + lane4);

        float d0 = c00.x*t0.x + c00.y*t0.y + c00.z*t0.z + c00.w*t0.w
                 + c01.x*t1.x + c01.y*t1.y + c01.z*t1.z + c01.w*t1.w;
        float d1 = c10.x*t0.x + c10.y*t0.y + c10.z*t0.z + c10.w*t0.w
                 + c11.x*t1.x + c11.y*t1.y + c11.z*t1.z + c11.w*t1.w;
        #pragma unroll
        for (int off = 1; off < 64; off <<= 1) {
            d0 += __shfl_xor(d0, off);
            d1 += __shfl_xor(d1, off);
        }

        const float sc0 = d0 * smask[rbase + 0];
        const float sc1 = d1 * smask[rbase + 1];
        if (lane == 0) ssc[rbase + 0] = sc0;
        if (lane == 1) ssc[rbase + 1] = sc1;

        const float mx = fmaxf(sc0, sc1);
        if (mx > m + 8.f) {                 // deferred-max rescale
            const float e = __expf(m - mx); // m==-inf -> 0
            l *= e;
            acc_a.x *= e; acc_a.y *= e; acc_a.z *= e; acc_a.w *= e;
            acc_b.x *= e; acc_b.y *= e; acc_b.z *= e; acc_b.w *= e;
            m = mx;
        }
        const float p0 = __expf(sc0 - m);
        const float p1 = __expf(sc1 - m);
        l += p0 + p1;

        acc_a.x += p0*c00.x + p1*c10.x;
        acc_a.y += p0*c00.y + p1*c10.y;
        acc_a.z += p0*c00.z + p1*c10.z;
        acc_a.w += p0*c00.w + p1*c10.w;
        acc_b.x += p0*c01.x + p1*c11.x;
        acc_b.y += p0*c01.y + p1*c11.y;
        acc_b.z += p0*c01.z + p1*c11.z;
        acc_b.w += p0*c01.w + p1*c11.w;
    }
    #undef ISSUE_TILE

    __syncthreads();                         // all waves done with tiles
    float* const lacc_w = tiles_w;           // overlay: 512 floats per wave
    if (lane == 0) { lm[wave] = m; ll[wave] = l; }
    *(float4*)(lacc_w + lane4) = acc_a;
    *(float4*)(lacc_w + 256 + lane4) = acc_b;
    __syncthreads();

    const float M = fmaxf(fmaxf(lm[0], lm[1]), fmaxf(lm[2], lm[3]));
    const float e0 = __expf(lm[0] - M);
    const float e1 = __expf(lm[1] - M);
    const float e2 = __expf(lm[2] - M);
    const float e3 = __expf(lm[3] - M);

    float* pml = ws + WS_PML + (size_t)(bi * CHUNKS + chunk) * 2;
    float* pacc = ws + WS_PACC + (size_t)(bi * CHUNKS + chunk) * HH;
    for (int h = threadIdx.x; h < HH; h += 256)
        pacc[h] = smem[0 * 2048 + h] * e0 + smem[1 * 2048 + h] * e1
                + smem[2 * 2048 + h] * e2 + smem[3 * 2048 + h] * e3;
    if (threadIdx.x == 0) {
        pml[0] = M;
        pml[1] = ll[0] * e0 + ll[1] * e1 + ll[2] * e2 + ll[3] * e3;
    }
    if (threadIdx.x < ROWS_PER_BLOCK)
        scores_g[chunk * ROWS_PER_BLOCK + threadIdx.x] = ssc[threadIdx.x];
}

// ------ K3: unified tail GEMV ; grid (16, 2, 32)
// x<8 : weighted halves — inline pml-merge, weighted slice in LDS, att write,
//       then 128-row W_out GEMV          (gi = (x>>2)*8 + (x&3))
// x>=8: input halves — tree_in/text_in 128-row W_out GEMV
//       (gi = seg*4 + slice, seg in {1,3})
__global__ __launch_bounds__(256) void k_tail2(
    const float* __restrict__ tree_in, const float* __restrict__ text_in,
    const float* __restrict__ W_out, const float* __restrict__ ws_ro,
    float* __restrict__ ws, float* __restrict__ out)
{
    const int x = blockIdx.x;
    const int half = blockIdx.y;
    const int b = blockIdx.z;
    const int tid = threadIdx.x;

    __shared__ float esc[CHUNKS];
    __shared__ float sw[128];

    int gi, row0;
    if (x < 8) {
        const int br = x >> 2;
        const int slice = x & 3;
        const int wseg = br * 2;          // comb segment 0 or 2
        gi = wseg * 4 + slice;
        row0 = wseg * 512 + slice * 128;
        const int bi = br * BB + b;

        // softmax merge constants from pml
        const float* pml = ws_ro + WS_PML + (size_t)bi * CHUNKS * 2;
        float M = -INFINITY;
        for (int c = 0; c < CHUNKS; ++c) M = fmaxf(M, pml[2 * c]);
        float L = 0.f;
        for (int c = 0; c < CHUNKS; ++c) L += pml[2 * c + 1] * __expf(pml[2 * c] - M);
        const float invL = 1.f / L;
        if (tid < CHUNKS) esc[tid] = __expf(pml[2 * tid] - M) * invL;
        __syncthreads();

        // weighted slice (128 h) from pacc -> LDS
        const float* pacc = ws_ro + WS_PACC + (size_t)bi * CHUNKS * HH;
        if (tid < 128) {
            const int h = slice * 128 + tid;
            float a = 0.f;
            for (int c = 0; c < CHUNKS; ++c) a += pacc[(size_t)c * HH + h] * esc[c];
            sw[tid] = a;
        }

        // att slice: 512 elements at (slice*2+half)*512
        const float* sc_g = ws_ro + WS_SCORES + (size_t)bi * SS;
        float* att = out + BB * HH + (size_t)bi * SS;
        const int s2 = (slice * 2 + half) * 512 + tid * 2;
        const float2 sc = *(const float2*)(sc_g + s2);
        float2 r;
        r.x = __expf(sc.x - M) * invL;
        r.y = __expf(sc.y - M) * invL;
        *(float2*)(att + s2) = r;
        __syncthreads();
    } else {
        const int rcp = x - 8;            // 0..7
        const int seg = (rcp < 4) ? 1 : 3;
        const int slice = rcp & 3;
        gi = seg * 4 + slice;
        row0 = seg * 512 + slice * 128;
        const float* src = (seg == 1 ? tree_in : text_in) + (size_t)b * HH;
        if (tid < 128) sw[tid] = src[slice * 128 + tid];
        __syncthreads();
    }

    // GEMV over the 128-row slice of W_out
    const float* wp = W_out + (size_t)row0 * HH + half * 256 + tid;
    float a = 0.f;
    #pragma unroll 8
    for (int j = 0; j < 128; ++j)
        a += sw[j] * wp[(size_t)j * HH];

    ws[WS_GPART + (size_t)((gi * 2 + half) * BB + b) * 256 + tid] = a;
}

// -------------------- K4: reduce partials + tanh ; grid (2,32)
__global__ __launch_bounds__(256) void k_fin(
    const float* __restrict__ ws, float* __restrict__ out)
{
    const int half = blockIdx.x;
    const int b = blockIdx.y;
    const int tid = threadIdx.x;
    float v = 0.f;
    #pragma unroll
    for (int gi = 0; gi < 16; ++gi)
        v += ws[WS_GPART + (size_t)((gi * 2 + half) * BB + b) * 256 + tid];
    out[(size_t)b * HH + half * 256 + tid] = tanhf(v);
}

// ---------------------------------------------------------------------- launch
extern "C" void kernel_launch(void* const* d_in, const int* in_sizes, int n_in,
                              void* d_out, int out_size, void* d_ws, size_t ws_size,
                              hipStream_t stream)
{
    const float* tree_inputs  = (const float*)d_in[0];
    const float* tree_context = (const float*)d_in[1];
    const float* text_inputs  = (const float*)d_in[2];
    const float* text_context = (const float*)d_in[3];
    const float* tree_mask    = (const float*)d_in[4];
    const float* text_mask    = (const float*)d_in[5];
    const float* W_in         = (const float*)d_in[6];
    const float* W_out        = (const float*)d_in[7];
    float* out = (float*)d_out;
    float* ws = (float*)d_ws;

    k_target<<<dim3(8, 64), 256, 0, stream>>>(tree_inputs, text_inputs, W_in, ws);
    k_flash<<<dim3(2, CHUNKS, BB), 256, 0, stream>>>(tree_context, text_context,
                                                     tree_mask, text_mask, ws);
    k_tail2<<<dim3(16, 2, BB), 256, 0, stream>>>(tree_inputs, text_inputs,
                                                 W_out, ws, ws, out);
    k_fin<<<dim3(2, BB), 256, 0, stream>>>(ws, out);
}